// Round 4
// baseline (380.775 us; speedup 1.0000x reference)
//
#include <hip/hip_runtime.h>
#include <cstdint>
#include <cstddef>

// Static problem geometry
#define LEN_IN  21760
#define BATCH   2
#define MROWS   (BATCH * LEN_IN)   // 43520 = 64 * 680
// Levels: (128,128),(64,64),(32,32),(16,16); starts 0,16384,20480,21504

typedef _Float16 hv8 __attribute__((ext_vector_type(8)));   // 8 f16
typedef float    fv4 __attribute__((ext_vector_type(4)));

// ---------------------------------------------------------------------------
// Weight prep: coalesced 64x64 LDS transpose. K-major [K][N] -> [N][K] f16.
// Woff -> f16-split: rows [0,256) = hi, [256,512) = lo residual.
// WaT lands contiguously after WoffT2 so the fused GEMM sees B rows 512..639.
// ---------------------------------------------------------------------------
__global__ __launch_bounds__(256) void cvt_weights(
    const float* __restrict__ Wv, const float* __restrict__ Woff,
    const float* __restrict__ Wa, const float* __restrict__ Wo,
    _Float16* __restrict__ WvT, _Float16* __restrict__ WoffT2,
    _Float16* __restrict__ WaT, _Float16* __restrict__ WoT)
{
  __shared__ float t[64][65];
  const int id = blockIdx.x, tid = threadIdx.x;
  const int c = tid & 63, r4 = tid >> 6;

  const float* src; _Float16* dst; int N; bool split = false; int nt, kt;
  if (id < 16)      { src = Wv;   dst = WvT;    N = 256; nt = id & 3;        kt = id >> 2; }
  else if (id < 32) { src = Woff; dst = WoffT2; N = 256; nt = (id - 16) & 3; kt = (id - 16) >> 2; split = true; }
  else if (id < 40) { src = Wa;   dst = WaT;    N = 128; nt = (id - 32) & 1; kt = (id - 32) >> 1; }
  else              { src = Wo;   dst = WoT;    N = 256; nt = (id - 40) & 3; kt = (id - 40) >> 2; }
  const int nb = nt * 64, kb = kt * 64;

#pragma unroll
  for (int rr = 0; rr < 16; ++rr) {
    const int r = rr * 4 + r4;
    t[r][c] = src[(size_t)(kb + r) * N + nb + c];
  }
  __syncthreads();
#pragma unroll
  for (int rr = 0; rr < 16; ++rr) {
    const int r = rr * 4 + r4;
    const float v = t[c][r];
    const _Float16 h = (_Float16)v;
    dst[(size_t)(nb + r) * 256 + kb + c] = h;
    if (split)
      dst[(size_t)(256 + nb + r) * 256 + kb + c] = (_Float16)(v - (float)h);
  }
}

// ---------------------------------------------------------------------------
// DIRECT-REGISTER f16 MFMA GEMM: no LDS, no barriers. K=256 is only 8
// MFMA K-steps; B panels (64-128 KB) are L2-resident across all 680 row
// blocks, so LDS staging was pure overhead (~5x roofline). Fragment layout
// for mfma_f32_16x16x32_f16 is directly loadable: lane reads
// [i*16 + (lane&15)][it*32 + (lane>>4)*8], 16B contiguous per lane.
// 64 x 128 tile, 4 waves x 32 cols. Fully unrolled: compiler pipelines
// the 48 loads across the 64 MFMAs with counted vmcnt.
// NTOT: full output width. AF32: A fp32 (cvt in regs) else f16.
// OUTMODE 0: fp32 row-major; 1: f16 row-major; 2: f16 head planes.
// ---------------------------------------------------------------------------
template<int NTOT, int AF32, int OUTMODE>
__global__ __launch_bounds__(256) void gemm_direct(
    const void* __restrict__ Ap, const _Float16* __restrict__ Bt,
    const float* __restrict__ bias, void* __restrict__ Cout)
{
  const int tid = threadIdx.x, lane = tid & 63, wave = tid >> 6;
  const int l15 = lane & 15, quad = lane >> 4;
  const int wc = wave * 32;
  const int rowBase = blockIdx.x * 64;
  const int colBase = blockIdx.y * 128;

  const float*    A32 = (const float*)Ap;
  const _Float16* A16 = (const _Float16*)Ap;

  fv4 acc[4][2] = {};

#pragma unroll
  for (int it = 0; it < 8; ++it) {
    const int k0 = it * 32 + quad * 8;

    hv8 af[4];
#pragma unroll
    for (int i = 0; i < 4; ++i) {
      const size_t rowoff = (size_t)(rowBase + i * 16 + l15) * 256 + k0;
      if constexpr (AF32) {
        const float4 f0 = *(const float4*)&A32[rowoff];
        const float4 f1 = *(const float4*)&A32[rowoff + 4];
        hv8 h;
        h[0] = (_Float16)f0.x; h[1] = (_Float16)f0.y;
        h[2] = (_Float16)f0.z; h[3] = (_Float16)f0.w;
        h[4] = (_Float16)f1.x; h[5] = (_Float16)f1.y;
        h[6] = (_Float16)f1.z; h[7] = (_Float16)f1.w;
        af[i] = h;
      } else {
        af[i] = *(const hv8*)&A16[rowoff];
      }
    }

#pragma unroll
    for (int j = 0; j < 2; ++j) {
      const hv8 bf = *(const hv8*)&Bt[(size_t)(colBase + wc + j * 16 + l15) * 256 + k0];
#pragma unroll
      for (int i = 0; i < 4; ++i)
        acc[i][j] = __builtin_amdgcn_mfma_f32_16x16x32_f16(af[i], bf, acc[i][j], 0, 0, 0);
    }
  }

#pragma unroll
  for (int j = 0; j < 2; ++j) {
    const int col = colBase + wc + j * 16 + l15;
    const float bj = bias[col];
#pragma unroll
    for (int i = 0; i < 4; ++i)
#pragma unroll
      for (int rg = 0; rg < 4; ++rg) {
        const int row = rowBase + i * 16 + quad * 4 + rg;
        const float v = acc[i][j][rg] + bj;
        if constexpr (OUTMODE == 0) {
          ((float*)Cout)[(size_t)row * NTOT + col] = v;
        } else if constexpr (OUTMODE == 1) {
          ((_Float16*)Cout)[(size_t)row * NTOT + col] = (_Float16)v;
        } else {
          const int n = (row >= LEN_IN) ? 1 : 0;
          const int pix = row - n * LEN_IN;
          const int m = col >> 5, d = col & 31;
          ((_Float16*)Cout)[((size_t)(n * 8 + m) * LEN_IN + pix) * 32 + d] = (_Float16)v;
        }
      }
  }
}

// ---------------------------------------------------------------------------
// FUSED offsets + logits GEMM, direct-register (no LDS / barriers).
// Grid (680, 3): y=0,1 -> offset coord columns, f16-split A and B (3 MFMAs).
// y=2 -> logits columns, plain hi-only path (1 MFMA), f16 out.
// B2 = [640][256] f16: rows 0..255 Woff-hi, 256..511 Woff-lo, 512..639 Wa.
// A fp32 loaded per-fragment and f16-split in regs (identical math to the
// staged version). Epilogue fuses (acc + boff + ref) * W - 0.5.
// ---------------------------------------------------------------------------
__global__ __launch_bounds__(256) void gemm_offs_logits(
    const float* __restrict__ A, const _Float16* __restrict__ B2,
    const float* __restrict__ boff, const float* __restrict__ ba,
    const float* __restrict__ refpts,
    float* __restrict__ C, _Float16* __restrict__ logits16)
{
  const bool offs = (blockIdx.y < 2);
  const int tid = threadIdx.x, lane = tid & 63, wave = tid >> 6;
  const int l15 = lane & 15, quad = lane >> 4;
  const int wc = wave * 32;
  const int rowBase = blockIdx.x * 64;
  const int colBase = offs ? blockIdx.y * 128 : 0;

  fv4 acc[4][2] = {};

#pragma unroll
  for (int it = 0; it < 8; ++it) {
    const int k0 = it * 32 + quad * 8;

    hv8 ah[4], al[4];
#pragma unroll
    for (int i = 0; i < 4; ++i) {
      const size_t rowoff = (size_t)(rowBase + i * 16 + l15) * 256 + k0;
      const float4 f0 = *(const float4*)&A[rowoff];
      const float4 f1 = *(const float4*)&A[rowoff + 4];
      const float fa[8] = {f0.x, f0.y, f0.z, f0.w, f1.x, f1.y, f1.z, f1.w};
      hv8 hh, ll;
#pragma unroll
      for (int e = 0; e < 8; ++e) {
        hh[e] = (_Float16)fa[e];
        ll[e] = (_Float16)(fa[e] - (float)hh[e]);
      }
      ah[i] = hh; al[i] = ll;
    }

    if (offs) {
#pragma unroll
      for (int j = 0; j < 2; ++j) {
        const int colr = colBase + wc + j * 16 + l15;
        const hv8 bh = *(const hv8*)&B2[(size_t)colr * 256 + k0];
        const hv8 bl = *(const hv8*)&B2[(size_t)(256 + colr) * 256 + k0];
#pragma unroll
        for (int i = 0; i < 4; ++i) {
          acc[i][j] = __builtin_amdgcn_mfma_f32_16x16x32_f16(ah[i], bh, acc[i][j], 0, 0, 0);
          acc[i][j] = __builtin_amdgcn_mfma_f32_16x16x32_f16(ah[i], bl, acc[i][j], 0, 0, 0);
          acc[i][j] = __builtin_amdgcn_mfma_f32_16x16x32_f16(al[i], bh, acc[i][j], 0, 0, 0);
        }
      }
    } else {
#pragma unroll
      for (int j = 0; j < 2; ++j) {
        const hv8 bh = *(const hv8*)&B2[(size_t)(512 + wc + j * 16 + l15) * 256 + k0];
#pragma unroll
        for (int i = 0; i < 4; ++i)
          acc[i][j] = __builtin_amdgcn_mfma_f32_16x16x32_f16(ah[i], bh, acc[i][j], 0, 0, 0);
      }
    }
  }

  if (offs) {
    // col c = (((m*4+l)*4+p)*2+xy); write (acc + boff + ref) * W - 0.5
#pragma unroll
    for (int j = 0; j < 2; ++j) {
      const int c = colBase + wc + j * 16 + l15;
      const int xy = c & 1, l = (c >> 3) & 3;
      const float Wl = (float)(128 >> l);
      const float bj = boff[c];
#pragma unroll
      for (int i = 0; i < 4; ++i)
#pragma unroll
        for (int rg = 0; rg < 4; ++rg) {
          const int row = rowBase + i * 16 + quad * 4 + rg;
          const float ref = refpts[(size_t)row * 8 + l * 2 + xy];
          C[(size_t)row * 256 + c] = (acc[i][j][rg] + bj + ref) * Wl - 0.5f;
        }
    }
  } else {
#pragma unroll
    for (int j = 0; j < 2; ++j) {
      const int col = wc + j * 16 + l15;
      const float bj = ba[col];
#pragma unroll
      for (int i = 0; i < 4; ++i)
#pragma unroll
        for (int rg = 0; rg < 4; ++rg) {
          const int row = rowBase + i * 16 + quad * 4 + rg;
          logits16[(size_t)row * 128 + col] = (_Float16)(acc[i][j][rg] + bj);
        }
    }
  }
}

// ---------------------------------------------------------------------------
// Sampler (R0 baseline body: immediate-consume gathers; both 2-deep register
// pipelines scratch-spilled ~1 GB, so keep the simple form — ~70 us floor).
// ---------------------------------------------------------------------------
__global__ __launch_bounds__(256, 8) void sample_kernel(
    const _Float16* __restrict__ value16,  // head planes
    const float* __restrict__ coords,      // (B, LQ, 256) pixel coords
    const _Float16* __restrict__ logits16, // (B, LQ, 128)
    _Float16* __restrict__ outp16)         // (B, LQ, 256)
{
  __shared__ unsigned s_pair[4096];
  __shared__ float    s_attn[1024];

  const int tid = threadIdx.x;
  const int qBase = blockIdx.x * 8;

  if (tid < 64) {   // softmax per (q,m) over 16
    const hv8* lp = (const hv8*)&logits16[(size_t)(qBase + (tid >> 3)) * 128 + (tid & 7) * 16];
    const hv8 w0 = lp[0], w1 = lp[1];
    float w[16];
#pragma unroll
    for (int e = 0; e < 8; ++e) { w[e] = (float)w0[e]; w[8 + e] = (float)w1[e]; }
    float mx = w[0];
#pragma unroll
    for (int i = 1; i < 16; ++i) mx = fmaxf(mx, w[i]);
    float sum = 0.f;
#pragma unroll
    for (int i = 0; i < 16; ++i) { w[i] = expf(w[i] - mx); sum += w[i]; }
    const float inv = 1.f / sum;
#pragma unroll
    for (int p = 0; p < 16; ++p) s_attn[p * 64 + tid] = w[p] * inv;
  }
  __syncthreads();

#pragma unroll
  for (int k = 0; k < 4; ++k) {
    const int i = tid + 256 * k;
    const int p = i >> 6, q = (i >> 3) & 7, m = i & 7;
    const int l = p >> 2, pp = p & 3;
    const int qg = qBase + q;
    const float2 of = *(const float2*)&coords[(size_t)qg * 256 + ((m * 4 + l) * 4 + pp) * 2];
    const float aw = s_attn[i];
    const int W = 128 >> l;
    const int st = (l == 0) ? 0 : (l == 1) ? 16384 : (l == 2) ? 20480 : 21504;
    const float xf = floorf(of.x), yf = floorf(of.y);
    const int x0 = (int)xf, y0 = (int)yf;
    const float wx = of.x - xf, wy = of.y - yf;
    uint4 rec;
    unsigned* rp = &rec.x;
#pragma unroll
    for (int c = 0; c < 4; ++c) {
      const int dx = c & 1, dy = c >> 1;
      const int xi = x0 + dx, yi = y0 + dy;
      const bool valid = (xi >= 0) & (xi < W) & (yi >= 0) & (yi < W);
      const float w = (dx ? wx : 1.f - wx) * (dy ? wy : 1.f - wy) * aw;
      union { _Float16 h; unsigned short s; } pk;
      pk.h = (_Float16)w;
      const unsigned idx = (unsigned)(st + yi * W + xi);
      rp[c] = valid ? (idx | ((unsigned)pk.s << 16)) : 0u;
    }
    *(uint4*)&s_pair[i * 4] = rec;
  }
  __syncthreads();

  const int wave = tid >> 6, lane = tid & 63;
  const int qloc = wave * 2 + (lane >> 5);
  const int sub = lane & 31, m = sub >> 2, j = sub & 3;
  const int qg = qBase + qloc;
  const int n = (qg >= LEN_IN) ? 1 : 0;
  const char* base = (const char*)value16 + (size_t)(n * 8 + m) * LEN_IN * 64 + j * 16;
  const int lb = qloc * 8 + m;

  float acc8[8] = {0.f, 0.f, 0.f, 0.f, 0.f, 0.f, 0.f, 0.f};
#pragma unroll 4
  for (int p = 0; p < 16; ++p) {
    const uint4 u4 = *(const uint4*)&s_pair[(p * 64 + lb) * 4];
    const unsigned uu[4] = {u4.x, u4.y, u4.z, u4.w};
#pragma unroll
    for (int c = 0; c < 4; ++c) {
      const unsigned u = uu[c];
      union { unsigned short s; _Float16 h; } pk;
      pk.s = (unsigned short)(u >> 16);
      const float w = (float)pk.h;
      const hv8 v = *(const hv8*)(base + (size_t)(u & 32767u) * 64);
#pragma unroll
      for (int e = 0; e < 8; ++e) acc8[e] = fmaf(w, (float)v[e], acc8[e]);
    }
  }

  hv8 o;
#pragma unroll
  for (int e = 0; e < 8; ++e) o[e] = (_Float16)acc8[e];
  *(hv8*)&outp16[(size_t)qg * 256 + m * 32 + j * 8] = o;
}

// ---------------------------------------------------------------------------
extern "C" void kernel_launch(void* const* d_in, const int* in_sizes, int n_in,
                              void* d_out, int out_size, void* d_ws, size_t ws_size,
                              hipStream_t stream) {
  const float* query   = (const float*)d_in[0];
  const float* refpts  = (const float*)d_in[1];
  const float* flatten = (const float*)d_in[2];
  const float* Wv   = (const float*)d_in[5];
  const float* bv   = (const float*)d_in[6];
  const float* Woff = (const float*)d_in[7];
  const float* boff = (const float*)d_in[8];
  const float* Wa   = (const float*)d_in[9];
  const float* ba   = (const float*)d_in[10];
  const float* Wo   = (const float*)d_in[11];
  const float* bo   = (const float*)d_in[12];
  float* out = (float*)d_out;

  // Workspace (~101 MB): value16 | coords | logits16 | outp16 | weights
  const size_t NE = (size_t)MROWS * 256;            // 11,141,120
  _Float16* value16  = (_Float16*)d_ws;             // NE halves (head planes)
  float*    coords   = (float*)(value16 + NE);      // NE floats
  _Float16* logits16 = (_Float16*)(coords + NE);    // NE/2 halves
  _Float16* outp16   = logits16 + NE / 2;           // NE halves
  _Float16* WvT      = outp16 + NE;                 // 256*256
  _Float16* WoffT2   = WvT + 256 * 256;             // 512*256 (hi|lo)
  _Float16* WaT      = WoffT2 + 512 * 256;          // 128*256 (contig after WoffT2!)
  _Float16* WoT      = WaT + 128 * 256;             // 256*256

  const dim3 blk(256);
  const int mtiles = MROWS / 64;   // 680

  cvt_weights<<<dim3(56), blk, 0, stream>>>(Wv, Woff, Wa, Wo, WvT, WoffT2, WaT, WoT);

  // value = f16(flatten @ Wv + bv) -> head planes
  gemm_direct<256, 1, 2><<<dim3(mtiles, 2), blk, 0, stream>>>(flatten, WvT, bv, value16);
  // FUSED: coords = (query @ Woff + boff + ref) * W - 0.5  AND
  //        logits = f16(query @ Wa + ba)   -- one pass over query
  gemm_offs_logits<<<dim3(mtiles, 3), blk, 0, stream>>>(query, WoffT2, boff, ba, refpts,
                                                        coords, logits16);
  // sampling -> out_pre (f16)
  sample_kernel<<<dim3(MROWS / 8), blk, 0, stream>>>(value16, coords, logits16, outp16);
  // out = out_pre @ Wo + bo (fp32 to d_out)
  gemm_direct<256, 0, 0><<<dim3(mtiles, 2), blk, 0, stream>>>(outp16, WoT, bo, out);
}

// Round 6
// 272.482 us; speedup vs baseline: 1.3974x; 1.3974x over previous
//
#include <hip/hip_runtime.h>
#include <cstdint>
#include <cstddef>

// Static problem geometry
#define LEN_IN  21760
#define BATCH   2
#define MROWS   (BATCH * LEN_IN)   // 43520 = 64 * 680
// Levels: (128,128),(64,64),(32,32),(16,16); starts 0,16384,20480,21504

typedef _Float16 hv8 __attribute__((ext_vector_type(8)));   // 8 f16
typedef float    fv4 __attribute__((ext_vector_type(4)));

#define WAIT_LGKM0() __builtin_amdgcn_s_waitcnt(0xC07F)   // lgkmcnt(0) only
#define RAW_BARRIER() __builtin_amdgcn_s_barrier()

// ---------------------------------------------------------------------------
// Weight prep: coalesced 64x64 LDS transpose. K-major [K][N] -> [N][K] f16.
// Woff -> f16-split: rows [0,256) = hi, [256,512) = lo residual.
// WaT lands contiguously after WoffT2 so the fused GEMM sees B rows 512..639.
// ---------------------------------------------------------------------------
__global__ __launch_bounds__(256) void cvt_weights(
    const float* __restrict__ Wv, const float* __restrict__ Woff,
    const float* __restrict__ Wa, const float* __restrict__ Wo,
    _Float16* __restrict__ WvT, _Float16* __restrict__ WoffT2,
    _Float16* __restrict__ WaT, _Float16* __restrict__ WoT)
{
  __shared__ float t[64][65];
  const int id = blockIdx.x, tid = threadIdx.x;
  const int c = tid & 63, r4 = tid >> 6;

  const float* src; _Float16* dst; int N; bool split = false; int nt, kt;
  if (id < 16)      { src = Wv;   dst = WvT;    N = 256; nt = id & 3;        kt = id >> 2; }
  else if (id < 32) { src = Woff; dst = WoffT2; N = 256; nt = (id - 16) & 3; kt = (id - 16) >> 2; split = true; }
  else if (id < 40) { src = Wa;   dst = WaT;    N = 128; nt = (id - 32) & 1; kt = (id - 32) >> 1; }
  else              { src = Wo;   dst = WoT;    N = 256; nt = (id - 40) & 3; kt = (id - 40) >> 2; }
  const int nb = nt * 64, kb = kt * 64;

#pragma unroll
  for (int rr = 0; rr < 16; ++rr) {
    const int r = rr * 4 + r4;
    t[r][c] = src[(size_t)(kb + r) * N + nb + c];
  }
  __syncthreads();
#pragma unroll
  for (int rr = 0; rr < 16; ++rr) {
    const int r = rr * 4 + r4;
    const float v = t[c][r];
    const _Float16 h = (_Float16)v;
    dst[(size_t)(nb + r) * 256 + kb + c] = h;
    if (split)
      dst[(size_t)(256 + nb + r) * 256 + kb + c] = (_Float16)(v - (float)h);
  }
}

// ---------------------------------------------------------------------------
// value-GEMM body (gemm_pipe<256,1,2> equivalent): 64x128 tile, LDS
// pipelined, A fp32 (cvt in regs), output f16 head planes. Carve:
// As[2] = sh[0..2560), sh[2560..5120); Bs[2] = sh[5120..10240), sh[10240..15360).
// ---------------------------------------------------------------------------
__device__ __forceinline__ void value_body(
    const float* __restrict__ A32, const _Float16* __restrict__ Bt,
    const float* __restrict__ bias, _Float16* __restrict__ Cout,
    _Float16* sh, int bx, int by, int tid)
{
  _Float16* As[2] = {sh, sh + 2560};
  _Float16* Bs[2] = {sh + 5120, sh + 10240};

  const int lane = tid & 63, wave = tid >> 6;
  const int l15 = lane & 15, quad = lane >> 4;
  const int wc = wave * 32;
  const int rowBase = bx * 64;
  const int colBase = by * 128;
  const int rs = tid >> 2, ks = (tid & 3) * 8;

  float4 pa[3][2]; hv8 pb[2][2];

  auto issueA = [&](int it) {
    const int k0 = it * 32, s = it % 3;
    pa[s][0] = *(const float4*)&A32[(size_t)(rowBase + rs) * 256 + k0 + ks];
    pa[s][1] = *(const float4*)&A32[(size_t)(rowBase + rs) * 256 + k0 + ks + 4];
  };
  auto issueB = [&](int it) {
    const int k0 = it * 32, s = it & 1;
#pragma unroll
    for (int p = 0; p < 2; ++p)
      pb[s][p] = *(const hv8*)&Bt[(size_t)(colBase + p * 64 + rs) * 256 + k0 + ks];
  };

  issueA(0); issueB(0); issueA(1); issueB(1); issueA(2);

  fv4 acc[4][2] = {};

#pragma unroll
  for (int it = 0; it < 8; ++it) {
    const int sb = it & 1, sa = it % 3;
    {
      const float4 f0 = pa[sa][0], f1 = pa[sa][1];
      const float fa[8] = {f0.x, f0.y, f0.z, f0.w, f1.x, f1.y, f1.z, f1.w};
      hv8 h;
#pragma unroll
      for (int e = 0; e < 8; ++e) h[e] = (_Float16)fa[e];
      *(hv8*)&As[sb][rs * 40 + ks] = h;
    }
#pragma unroll
    for (int p = 0; p < 2; ++p)
      *(hv8*)&Bs[sb][(p * 64 + rs) * 40 + ks] = pb[sb][p];
    if (it + 2 < 8) issueB(it + 2);   // need order: B first,
    if (it + 3 < 8) issueA(it + 3);   // then A
    WAIT_LGKM0();
    RAW_BARRIER();

    hv8 af[4];
#pragma unroll
    for (int i = 0; i < 4; ++i)
      af[i] = *(const hv8*)&As[sb][(i * 16 + l15) * 40 + quad * 8];
#pragma unroll
    for (int j = 0; j < 2; ++j) {
      const hv8 bf = *(const hv8*)&Bs[sb][(wc + j * 16 + l15) * 40 + quad * 8];
#pragma unroll
      for (int i = 0; i < 4; ++i)
        acc[i][j] = __builtin_amdgcn_mfma_f32_16x16x32_f16(af[i], bf, acc[i][j], 0, 0, 0);
    }
  }

#pragma unroll
  for (int j = 0; j < 2; ++j) {
    const int col = colBase + wc + j * 16 + l15;
    const float bj = bias[col];
#pragma unroll
    for (int i = 0; i < 4; ++i)
#pragma unroll
      for (int rg = 0; rg < 4; ++rg) {
        const int row = rowBase + i * 16 + quad * 4 + rg;
        const float v = acc[i][j][rg] + bj;
        const int n = (row >= LEN_IN) ? 1 : 0;
        const int pix = row - n * LEN_IN;
        const int m = col >> 5, d = col & 31;
        Cout[((size_t)(n * 8 + m) * LEN_IN + pix) * 32 + d] = (_Float16)v;
      }
  }
}

// ---------------------------------------------------------------------------
// offs/logits body: oy=0,1 -> offset coords (f16-split, 3 MFMAs);
// oy=2 -> logits (1 MFMA). Carve: Ash=sh[0..2560), Asl=sh[2560..5120),
// Bs=sh[5120..15360).
// ---------------------------------------------------------------------------
__device__ __forceinline__ void offs_body(
    const float* __restrict__ A, const _Float16* __restrict__ B2,
    const float* __restrict__ boff, const float* __restrict__ ba,
    const float* __restrict__ refpts,
    float* __restrict__ C, _Float16* __restrict__ logits16,
    _Float16* sh, int bx, int oy, int tid)
{
  _Float16* Ash = sh;
  _Float16* Asl = sh + 2560;
  _Float16* Bs  = sh + 5120;   // offs: rows 0-127 hi, 128-255 lo. logits: rows 0-127.

  const bool offs = (oy < 2);
  const int np = offs ? 4 : 2;
  const int lane = tid & 63, wave = tid >> 6;
  const int l15 = lane & 15, quad = lane >> 4;
  const int wc = wave * 32;
  const int rowBase = bx * 64;
  const int colBase = offs ? oy * 128 : 0;
  const int rs = tid >> 2, ks = (tid & 3) * 8;

  float4 pa[3][2]; hv8 pb[2][4];

  auto issueA = [&](int it) {
    const int k0 = it * 32, s = it % 3;
    pa[s][0] = *(const float4*)&A[(size_t)(rowBase + rs) * 256 + k0 + ks];
    pa[s][1] = *(const float4*)&A[(size_t)(rowBase + rs) * 256 + k0 + ks + 4];
  };
  auto issueB = [&](int it) {
    const int k0 = it * 32, s = it & 1;
#pragma unroll
    for (int p = 0; p < 4; ++p) {
      if (p >= np) break;
      const int grow = offs
          ? ((p < 2) ? (colBase + p * 64 + rs) : (256 + colBase + (p - 2) * 64 + rs))
          : (512 + p * 64 + rs);
      pb[s][p] = *(const hv8*)&B2[(size_t)grow * 256 + k0 + ks];
    }
  };

  issueA(0); issueB(0); issueA(1); issueB(1); issueA(2);

  fv4 acc[4][2] = {};

#pragma unroll
  for (int it = 0; it < 8; ++it) {
    const int sa = it % 3, s2 = it & 1;
    {
      const float4 f0 = pa[sa][0], f1 = pa[sa][1];
      const float fa[8] = {f0.x, f0.y, f0.z, f0.w, f1.x, f1.y, f1.z, f1.w};
      hv8 hh, ll;
#pragma unroll
      for (int e = 0; e < 8; ++e) {
        hh[e] = (_Float16)fa[e];
        ll[e] = (_Float16)(fa[e] - (float)hh[e]);
      }
      *(hv8*)&Ash[rs * 40 + ks] = hh;
      if (offs) *(hv8*)&Asl[rs * 40 + ks] = ll;
    }
#pragma unroll
    for (int p = 0; p < 4; ++p) {
      if (p >= np) break;
      *(hv8*)&Bs[(p * 64 + rs) * 40 + ks] = pb[s2][p];
    }
    if (it + 2 < 8) issueB(it + 2);
    if (it + 3 < 8) issueA(it + 3);
    WAIT_LGKM0();
    RAW_BARRIER();

    hv8 ah[4];
#pragma unroll
    for (int i = 0; i < 4; ++i)
      ah[i] = *(const hv8*)&Ash[(i * 16 + l15) * 40 + quad * 8];

    if (offs) {
      hv8 al[4];
#pragma unroll
      for (int i = 0; i < 4; ++i)
        al[i] = *(const hv8*)&Asl[(i * 16 + l15) * 40 + quad * 8];
#pragma unroll
      for (int j = 0; j < 2; ++j) {
        const hv8 bh = *(const hv8*)&Bs[(wc + j * 16 + l15) * 40 + quad * 8];
        const hv8 bl = *(const hv8*)&Bs[(128 + wc + j * 16 + l15) * 40 + quad * 8];
#pragma unroll
        for (int i = 0; i < 4; ++i) {
          acc[i][j] = __builtin_amdgcn_mfma_f32_16x16x32_f16(ah[i], bh, acc[i][j], 0, 0, 0);
          acc[i][j] = __builtin_amdgcn_mfma_f32_16x16x32_f16(ah[i], bl, acc[i][j], 0, 0, 0);
          acc[i][j] = __builtin_amdgcn_mfma_f32_16x16x32_f16(al[i], bh, acc[i][j], 0, 0, 0);
        }
      }
    } else {
#pragma unroll
      for (int j = 0; j < 2; ++j) {
        const hv8 bh = *(const hv8*)&Bs[(wc + j * 16 + l15) * 40 + quad * 8];
#pragma unroll
        for (int i = 0; i < 4; ++i)
          acc[i][j] = __builtin_amdgcn_mfma_f32_16x16x32_f16(ah[i], bh, acc[i][j], 0, 0, 0);
      }
    }
    WAIT_LGKM0();   // frag reads done before next iter overwrites (single buf)
    RAW_BARRIER();
  }

  if (offs) {
#pragma unroll
    for (int j = 0; j < 2; ++j) {
      const int c = colBase + wc + j * 16 + l15;
      const int xy = c & 1, l = (c >> 3) & 3;
      const float Wl = (float)(128 >> l);
      const float bj = boff[c];
#pragma unroll
      for (int i = 0; i < 4; ++i)
#pragma unroll
        for (int rg = 0; rg < 4; ++rg) {
          const int row = rowBase + i * 16 + quad * 4 + rg;
          const float ref = refpts[(size_t)row * 8 + l * 2 + xy];
          C[(size_t)row * 256 + c] = (acc[i][j][rg] + bj + ref) * Wl - 0.5f;
        }
    }
  } else {
#pragma unroll
    for (int j = 0; j < 2; ++j) {
      const int col = wc + j * 16 + l15;
      const float bj = ba[col];
#pragma unroll
      for (int i = 0; i < 4; ++i)
#pragma unroll
        for (int rg = 0; rg < 4; ++rg) {
          const int row = rowBase + i * 16 + quad * 4 + rg;
          logits16[(size_t)row * 128 + col] = (_Float16)(acc[i][j][rg] + bj);
        }
    }
  }
}

// ---------------------------------------------------------------------------
// MERGED front dispatch: value GEMM (blocks 0..1359) + offs/logits GEMM
// (blocks 1360..3399) in ONE kernel. Independent inputs; both must precede
// the sampler. Both bodies use the same 30720 B LDS carve.
// ---------------------------------------------------------------------------
__global__ __launch_bounds__(256) void gemm_front(
    const float* __restrict__ flatten, const _Float16* __restrict__ WvT,
    const float* __restrict__ bv, _Float16* __restrict__ value16,
    const float* __restrict__ query, const _Float16* __restrict__ B2,
    const float* __restrict__ boff, const float* __restrict__ ba,
    const float* __restrict__ refpts,
    float* __restrict__ coords, _Float16* __restrict__ logits16)
{
  __shared__ _Float16 sh[15360];   // 30720 B, carved per body
  const int id = blockIdx.x, tid = threadIdx.x;
  if (id < 1360) {
    value_body(flatten, WvT, bv, value16, sh, id % 680, id / 680, tid);
  } else {
    const int oid = id - 1360;
    offs_body(query, B2, boff, ba, refpts, coords, logits16, sh,
              oid % 680, oid / 680, tid);
  }
}

// ---------------------------------------------------------------------------
// Final GEMM (R3 gemm_pipe<256,0,0>): A f16 (outp16), fp32 row-major out.
// ---------------------------------------------------------------------------
__global__ __launch_bounds__(256) void gemm_final(
    const _Float16* __restrict__ A16, const _Float16* __restrict__ Bt,
    const float* __restrict__ bias, float* __restrict__ Cout)
{
  __shared__ _Float16 As[2][64 * 40];
  __shared__ _Float16 Bs[2][128 * 40];

  const int tid = threadIdx.x, lane = tid & 63, wave = tid >> 6;
  const int l15 = lane & 15, quad = lane >> 4;
  const int wc = wave * 32;
  const int rowBase = blockIdx.x * 64;
  const int colBase = blockIdx.y * 128;
  const int rs = tid >> 2, ks = (tid & 3) * 8;

  hv8 pa16[3]; hv8 pb[2][2];

  auto issueA = [&](int it) {
    const int k0 = it * 32, s = it % 3;
    pa16[s] = *(const hv8*)&A16[(size_t)(rowBase + rs) * 256 + k0 + ks];
  };
  auto issueB = [&](int it) {
    const int k0 = it * 32, s = it & 1;
#pragma unroll
    for (int p = 0; p < 2; ++p)
      pb[s][p] = *(const hv8*)&Bt[(size_t)(colBase + p * 64 + rs) * 256 + k0 + ks];
  };

  issueA(0); issueB(0); issueA(1); issueB(1); issueA(2);

  fv4 acc[4][2] = {};

#pragma unroll
  for (int it = 0; it < 8; ++it) {
    const int sb = it & 1, sa = it % 3;
    *(hv8*)&As[sb][rs * 40 + ks] = pa16[sa];
#pragma unroll
    for (int p = 0; p < 2; ++p)
      *(hv8*)&Bs[sb][(p * 64 + rs) * 40 + ks] = pb[sb][p];
    if (it + 2 < 8) issueB(it + 2);   // need order: B first,
    if (it + 3 < 8) issueA(it + 3);   // then A
    WAIT_LGKM0();
    RAW_BARRIER();

    hv8 af[4];
#pragma unroll
    for (int i = 0; i < 4; ++i)
      af[i] = *(const hv8*)&As[sb][(i * 16 + l15) * 40 + quad * 8];
#pragma unroll
    for (int j = 0; j < 2; ++j) {
      const hv8 bf = *(const hv8*)&Bs[sb][(wc + j * 16 + l15) * 40 + quad * 8];
#pragma unroll
      for (int i = 0; i < 4; ++i)
        acc[i][j] = __builtin_amdgcn_mfma_f32_16x16x32_f16(af[i], bf, acc[i][j], 0, 0, 0);
    }
  }

#pragma unroll
  for (int j = 0; j < 2; ++j) {
    const int col = colBase + wc + j * 16 + l15;
    const float bj = bias[col];
#pragma unroll
    for (int i = 0; i < 4; ++i)
#pragma unroll
      for (int rg = 0; rg < 4; ++rg) {
        const int row = rowBase + i * 16 + quad * 4 + rg;
        Cout[(size_t)row * 256 + col] = acc[i][j][rg] + bj;
      }
  }
}

// ---------------------------------------------------------------------------
// Sampler (R3-proven body: immediate-consume gathers, ~70 us floor).
// ---------------------------------------------------------------------------
__global__ __launch_bounds__(256, 8) void sample_kernel(
    const _Float16* __restrict__ value16,  // head planes
    const float* __restrict__ coords,      // (B, LQ, 256) pixel coords
    const _Float16* __restrict__ logits16, // (B, LQ, 128)
    _Float16* __restrict__ outp16)         // (B, LQ, 256)
{
  __shared__ unsigned s_pair[4096];
  __shared__ float    s_attn[1024];

  const int tid = threadIdx.x;
  const int qBase = blockIdx.x * 8;

  if (tid < 64) {   // softmax per (q,m) over 16
    const hv8* lp = (const hv8*)&logits16[(size_t)(qBase + (tid >> 3)) * 128 + (tid & 7) * 16];
    const hv8 w0 = lp[0], w1 = lp[1];
    float w[16];
#pragma unroll
    for (int e = 0; e < 8; ++e) { w[e] = (float)w0[e]; w[8 + e] = (float)w1[e]; }
    float mx = w[0];
#pragma unroll
    for (int i = 1; i < 16; ++i) mx = fmaxf(mx, w[i]);
    float sum = 0.f;
#pragma unroll
    for (int i = 0; i < 16; ++i) { w[i] = expf(w[i] - mx); sum += w[i]; }
    const float inv = 1.f / sum;
#pragma unroll
    for (int p = 0; p < 16; ++p) s_attn[p * 64 + tid] = w[p] * inv;
  }
  __syncthreads();

#pragma unroll
  for (int k = 0; k < 4; ++k) {
    const int i = tid + 256 * k;
    const int p = i >> 6, q = (i >> 3) & 7, m = i & 7;
    const int l = p >> 2, pp = p & 3;
    const int qg = qBase + q;
    const float2 of = *(const float2*)&coords[(size_t)qg * 256 + ((m * 4 + l) * 4 + pp) * 2];
    const float aw = s_attn[i];
    const int W = 128 >> l;
    const int st = (l == 0) ? 0 : (l == 1) ? 16384 : (l == 2) ? 20480 : 21504;
    const float xf = floorf(of.x), yf = floorf(of.y);
    const int x0 = (int)xf, y0 = (int)yf;
    const float wx = of.x - xf, wy = of.y - yf;
    uint4 rec;
    unsigned* rp = &rec.x;
#pragma unroll
    for (int c = 0; c < 4; ++c) {
      const int dx = c & 1, dy = c >> 1;
      const int xi = x0 + dx, yi = y0 + dy;
      const bool valid = (xi >= 0) & (xi < W) & (yi >= 0) & (yi < W);
      const float w = (dx ? wx : 1.f - wx) * (dy ? wy : 1.f - wy) * aw;
      union { _Float16 h; unsigned short s; } pk;
      pk.h = (_Float16)w;
      const unsigned idx = (unsigned)(st + yi * W + xi);
      rp[c] = valid ? (idx | ((unsigned)pk.s << 16)) : 0u;
    }
    *(uint4*)&s_pair[i * 4] = rec;
  }
  __syncthreads();

  const int wave = tid >> 6, lane = tid & 63;
  const int qloc = wave * 2 + (lane >> 5);
  const int sub = lane & 31, m = sub >> 2, j = sub & 3;
  const int qg = qBase + qloc;
  const int n = (qg >= LEN_IN) ? 1 : 0;
  const char* base = (const char*)value16 + (size_t)(n * 8 + m) * LEN_IN * 64 + j * 16;
  const int lb = qloc * 8 + m;

  float acc8[8] = {0.f, 0.f, 0.f, 0.f, 0.f, 0.f, 0.f, 0.f};
#pragma unroll 4
  for (int p = 0; p < 16; ++p) {
    const uint4 u4 = *(const uint4*)&s_pair[(p * 64 + lb) * 4];
    const unsigned uu[4] = {u4.x, u4.y, u4.z, u4.w};
#pragma unroll
    for (int c = 0; c < 4; ++c) {
      const unsigned u = uu[c];
      union { unsigned short s; _Float16 h; } pk;
      pk.s = (unsigned short)(u >> 16);
      const float w = (float)pk.h;
      const hv8 v = *(const hv8*)(base + (size_t)(u & 32767u) * 64);
#pragma unroll
      for (int e = 0; e < 8; ++e) acc8[e] = fmaf(w, (float)v[e], acc8[e]);
    }
  }

  hv8 o;
#pragma unroll
  for (int e = 0; e < 8; ++e) o[e] = (_Float16)acc8[e];
  *(hv8*)&outp16[(size_t)qg * 256 + m * 32 + j * 8] = o;
}

// ---------------------------------------------------------------------------
extern "C" void kernel_launch(void* const* d_in, const int* in_sizes, int n_in,
                              void* d_out, int out_size, void* d_ws, size_t ws_size,
                              hipStream_t stream) {
  const float* query   = (const float*)d_in[0];
  const float* refpts  = (const float*)d_in[1];
  const float* flatten = (const float*)d_in[2];
  const float* Wv   = (const float*)d_in[5];
  const float* bv   = (const float*)d_in[6];
  const float* Woff = (const float*)d_in[7];
  const float* boff = (const float*)d_in[8];
  const float* Wa   = (const float*)d_in[9];
  const float* ba   = (const float*)d_in[10];
  const float* Wo   = (const float*)d_in[11];
  const float* bo   = (const float*)d_in[12];
  float* out = (float*)d_out;

  // Workspace (~101 MB): value16 | coords | logits16 | outp16 | weights
  const size_t NE = (size_t)MROWS * 256;            // 11,141,120
  _Float16* value16  = (_Float16*)d_ws;             // NE halves (head planes)
  float*    coords   = (float*)(value16 + NE);      // NE floats
  _Float16* logits16 = (_Float16*)(coords + NE);    // NE/2 halves
  _Float16* outp16   = logits16 + NE / 2;           // NE halves
  _Float16* WvT      = outp16 + NE;                 // 256*256
  _Float16* WoffT2   = WvT + 256 * 256;             // 512*256 (hi|lo)
  _Float16* WaT      = WoffT2 + 512 * 256;          // 128*256 (contig after WoffT2!)
  _Float16* WoT      = WaT + 128 * 256;             // 256*256

  const dim3 blk(256);
  const int mtiles = MROWS / 64;   // 680

  cvt_weights<<<dim3(56), blk, 0, stream>>>(Wv, Woff, Wa, Wo, WvT, WoffT2, WaT, WoT);

  // MERGED: value = f16(flatten @ Wv + bv) -> head planes  (blocks 0..1359)
  //         coords = (query @ Woff + boff + ref) * W - 0.5 (blocks 1360..2719)
  //         logits = f16(query @ Wa + ba)                  (blocks 2720..3399)
  gemm_front<<<dim3(3400), blk, 0, stream>>>(flatten, WvT, bv, value16,
                                             query, WoffT2, boff, ba, refpts,
                                             coords, logits16);

  // sampling -> out_pre (f16)
  sample_kernel<<<dim3(MROWS / 8), blk, 0, stream>>>(value16, coords, logits16, outp16);

  // out = out_pre @ Wo + bo (fp32 to d_out)
  gemm_final<<<dim3(mtiles, 2), blk, 0, stream>>>(outp16, WoT, bo, out);
}